// Round 1
// baseline (305.786 us; speedup 1.0000x reference)
//
#include <hip/hip_runtime.h>
#include <math.h>

#define E_DIM 1024
#define B_DIM 4
#define S_DIM 2048
#define H_DIM 16
#define D_HEAD 64
#define M_DIM (B_DIM * S_DIM)   // 8192
#define LOG2E 1.44269504f
#define RESCALE_THR 4.0f        // defer-max threshold (exp2 domain): P <= 2^4

typedef _Float16 half8 __attribute__((ext_vector_type(8)));
typedef _Float16 half4 __attribute__((ext_vector_type(4)));
typedef __fp16  fp16x2 __attribute__((ext_vector_type(2)));   // cvt_pkrtz return type
typedef float floatx4 __attribute__((ext_vector_type(4)));
#define MFMA_F16(a, b, c) __builtin_amdgcn_mfma_f32_16x16x32_f16(a, b, c, 0, 0, 0)

#if __has_builtin(__builtin_amdgcn_exp2f)
#define EXP2F(x) __builtin_amdgcn_exp2f(x)
#else
#define EXP2F(x) exp2f(x)
#endif

union H4 { fp16x2 h2[2]; half4 h4; };

// async global->LDS, 16B per lane; LDS dest = wave-uniform base + lane*16B
#define GLDS16(g, l)                                                          \
    __builtin_amdgcn_global_load_lds(                                         \
        (const __attribute__((address_space(1))) void*)(g),                   \
        (__attribute__((address_space(3))) void*)(l), 16, 0, 0)

// Split-K segment work list (40 segs per bh), sorted heavy-first.
// nseg(qb) = qb/4 + 1; seg covers chunks [8s, min(8s+8, 2qb+2)) of 64 keys.
__device__ const int SEG_QBLK[40] = {3,4,5,6,7,7,8,8,9,9,10,10,11,11,11,12,12,12,
                                     13,13,13,14,14,14,15,15,15,15,
                                     2,6,10,14, 1,5,9,13, 0,4,8,12};
__device__ const int SEG_SEG[40]  = {0,0,0,0,0,1,0,1,0,1,0,1,0,1,2,0,1,2,
                                     0,1,2,0,1,2,0,1,2,3,
                                     0,1,2,3, 0,1,2,3, 0,1,2,3};
__device__ const int SEG_BASE[16] = {0,1,2,3,4,6,8,10,12,15,18,21,24,28,32,36};

// ---------------- x: fp32 -> fp16 cast copy ----------------
__global__ __launch_bounds__(256) void cvt_x(
    const float* __restrict__ X, _Float16* __restrict__ Xh)
{
    size_t i = ((size_t)blockIdx.x * 256 + threadIdx.x) * 8;
    float4 a = *(const float4*)&X[i];
    float4 b = *(const float4*)&X[i + 4];
    half8 h = {(_Float16)a.x, (_Float16)a.y, (_Float16)a.z, (_Float16)a.w,
               (_Float16)b.x, (_Float16)b.y, (_Float16)b.z, (_Float16)b.w};
    *(half8*)&Xh[i] = h;
}

// ---------------- W: fp32 [k][n] -> fp16 [n][k] transpose ----------------
__global__ __launch_bounds__(256) void cvt_w(
    const float* __restrict__ W0, const float* __restrict__ W1,
    const float* __restrict__ W2, const float* __restrict__ W3,
    _Float16* __restrict__ T0, _Float16* __restrict__ T1,
    _Float16* __restrict__ T2, _Float16* __restrict__ T3)
{
    const int z = blockIdx.z;
    const float* W = (z == 0) ? W0 : (z == 1) ? W1 : (z == 2) ? W2 : W3;
    _Float16*   T  = (z == 0) ? T0 : (z == 1) ? T1 : (z == 2) ? T2 : T3;
    const int k0 = blockIdx.x * 64, n0 = blockIdx.y * 64;
    const int tid = threadIdx.x;
    __shared__ float t[64][65];
#pragma unroll
    for (int it = 0; it < 4; it++) {
        int r = it * 16 + (tid >> 4);
        int c = (tid & 15) * 4;
        float4 v = *(const float4*)&W[(size_t)(k0 + r) * E_DIM + n0 + c];
        t[r][c] = v.x; t[r][c + 1] = v.y; t[r][c + 2] = v.z; t[r][c + 3] = v.w;
    }
    __syncthreads();
#pragma unroll
    for (int it = 0; it < 2; it++) {
        int n = it * 32 + (tid >> 3);
        int kk = (tid & 7) * 8;
        half8 h;
#pragma unroll
        for (int j = 0; j < 8; j++) h[j] = (_Float16)t[kk + j][n];
        *(half8*)&T[(size_t)(n0 + n) * E_DIM + k0 + kk] = h;
    }
}

// ---------------- MFMA GEMM core (m97 structure) ----------------
#define GEMM_CORE(Aptr, Bptr)                                                 \
    const int tid = threadIdx.x;                                              \
    const int wave = tid >> 6, lane = tid & 63;                               \
    const int m16 = lane & 15, quad = lane >> 4;                              \
    const int wm = (wave >> 1) * 64, wn = (wave & 1) * 64;                    \
    const int m0 = blockIdx.x * 128, n0 = blockIdx.y * 128;                   \
    __shared__ _Float16 As[128 * 32];                                         \
    __shared__ _Float16 Bs[128 * 32];                                         \
    floatx4 acc[4][4];                                                        \
    const floatx4 zf = {0.f, 0.f, 0.f, 0.f};                                  \
    _Pragma("unroll") for (int i = 0; i < 4; i++)                             \
        _Pragma("unroll") for (int j = 0; j < 4; j++) acc[i][j] = zf;         \
    const int lrow = lane >> 2, lseg = lane & 3;                              \
    const _Float16* gA = (Aptr) + (size_t)(m0 + wave * 32 + lrow) * E_DIM + lseg * 8; \
    const _Float16* gB = (Bptr) + (size_t)(n0 + wave * 32 + lrow) * E_DIM + lseg * 8; \
    _Float16* lA = As + (wave * 32) * 32;                                     \
    _Float16* lB = Bs + (wave * 32) * 32;                                     \
    for (int k0 = 0; k0 < E_DIM; k0 += 32) {                                  \
        __syncthreads();                                                      \
        GLDS16(gA + k0, lA);                                                  \
        GLDS16(gA + 16 * E_DIM + k0, lA + 16 * 32);                           \
        GLDS16(gB + k0, lB);                                                  \
        GLDS16(gB + 16 * E_DIM + k0, lB + 16 * 32);                           \
        __syncthreads();                                                      \
        half8 af[4], bf[4];                                                   \
        _Pragma("unroll") for (int mt = 0; mt < 4; mt++)                      \
            af[mt] = *(const half8*)&As[(wm + mt * 16 + m16) * 32 + quad * 8];\
        _Pragma("unroll") for (int nt = 0; nt < 4; nt++)                      \
            bf[nt] = *(const half8*)&Bs[(wn + nt * 16 + m16) * 32 + quad * 8];\
        _Pragma("unroll") for (int mt = 0; mt < 4; mt++)                      \
            _Pragma("unroll") for (int nt = 0; nt < 4; nt++)                  \
                acc[mt][nt] = MFMA_F16(af[mt], bf[nt], acc[mt][nt]);          \
    }

// QKV projection epilogues write FRAGMENT-ORDERED blobs so attn_mfma can load
// MFMA operands directly from global (16B/lane, fully coalesced per (tile)):
//  Q blob: per (bh,qblk128): [sub=qq>>4][dh][lane][8]  lane=qd*16|lq, j=d&7
//          pre-scaled by 0.125*log2(e) (exp2-domain softmax)
//  K blob: per (bh,kc64):    [kt][dh][lane][8]         lane=qd*16|lk, j=d&7
//  V blob: per (bh,kc64):    [dt][kh][lane][8]         lane=q8*16|ld, j=key&7
__global__ __launch_bounds__(256) void qkv_mfma(
    const _Float16* __restrict__ Xh,
    const _Float16* __restrict__ Tq, const float* __restrict__ bq,
    const _Float16* __restrict__ Tk, const float* __restrict__ bk,
    const _Float16* __restrict__ Tv, const float* __restrict__ bv,
    _Float16* __restrict__ Qo, _Float16* __restrict__ Ko, _Float16* __restrict__ Vo)
{
    const int z = blockIdx.z;
    const _Float16* Wt   = (z == 0) ? Tq : (z == 1) ? Tk : Tv;
    const float*    bias = (z == 0) ? bq : (z == 1) ? bk : bv;

    GEMM_CORE(Xh, Wt)

    if (z == 2) {
        // V blob: A-fragment order for PV (V^T tiles); half4 along key (r)
#pragma unroll
        for (int nt = 0; nt < 4; nt++) {
            int n = n0 + wn + nt * 16 + m16;
            int h = n >> 6, d = n & 63;
            int dt = d >> 4, ld = d & 15;
            float bias_v = bias[n];
#pragma unroll
            for (int mt = 0; mt < 4; mt++) {
                int m_b = m0 + wm + mt * 16 + quad * 4;
                int b = m_b >> 11, s = m_b & 2047;
                int bh = b * H_DIM + h;
                int c = s >> 6, kl = s & 63;
                int kh = kl >> 5, q8 = (kl >> 3) & 3, j0 = kl & 7;
                size_t off = ((size_t)bh * 32 + c) * 4096
                           + (size_t)(((dt * 2 + kh) * 64 + q8 * 16 + ld) * 8 + j0);
                half4 hv;
#pragma unroll
                for (int r = 0; r < 4; r++) hv[r] = (_Float16)(acc[mt][nt][r] + bias_v);
                *(half4*)&Vo[off] = hv;
            }
        }
    } else {
        _Float16* Out = (z == 0) ? Qo : Ko;
        const float sc = (z == 0) ? 0.125f * LOG2E : 1.0f;
#pragma unroll
        for (int nt = 0; nt < 4; nt++) {
            int n = n0 + wn + nt * 16 + m16;
            int h = n >> 6, d = n & 63;
            int dh = d >> 5, qd = (d >> 3) & 3, j = d & 7;
            float bias_v = bias[n];
#pragma unroll
            for (int mt = 0; mt < 4; mt++) {
#pragma unroll
                for (int r = 0; r < 4; r++) {
                    int m = m0 + wm + mt * 16 + quad * 4 + r;
                    int b = m >> 11, s = m & 2047;
                    int bh = b * H_DIM + h;
                    size_t off;
                    if (z == 0) {
                        int qblk = s >> 7, qq = s & 127;
                        int sub = qq >> 4, lq = qq & 15;
                        off = ((size_t)bh * 16 + qblk) * 8192
                            + (size_t)(((sub * 2 + dh) * 64 + qd * 16 + lq) * 8 + j);
                    } else {
                        int c = s >> 6, kl = s & 63;
                        int kt = kl >> 4, lk = kl & 15;
                        off = ((size_t)bh * 32 + c) * 4096
                            + (size_t)(((kt * 2 + dh) * 64 + qd * 16 + lk) * 8 + j);
                    }
                    Out[off] = (_Float16)((acc[mt][nt][r] + bias_v) * sc);
                }
            }
        }
    }
}

// Output projection: A = O fp16 [M][E], writes fp32 [M][E]
__global__ __launch_bounds__(256) void out_mfma(
    const _Float16* __restrict__ Oh, const _Float16* __restrict__ To,
    const float* __restrict__ bias, float* __restrict__ Out)
{
    GEMM_CORE(Oh, To)

#pragma unroll
    for (int nt = 0; nt < 4; nt++) {
        int n = n0 + wn + nt * 16 + m16;
        float bias_v = bias[n];
#pragma unroll
        for (int mt = 0; mt < 4; mt++) {
#pragma unroll
            for (int r = 0; r < 4; r++) {
                int m = m0 + wm + mt * 16 + quad * 4 + r;
                Out[(size_t)m * E_DIM + n] = acc[mt][nt][r] + bias_v;
            }
        }
    }
}

// ---------------- Split-K MFMA causal flash attention ----------------
// Barrier-free: K/V/Q fragments loaded DIRECTLY from fragment-ordered global
// blobs (no shared staging -> no __syncthreads; waves fully independent with
// per-wave causal cutoff). LDS holds only the per-wave P scratch (16 KB).
// K is register-prefetched one chunk ahead; V loads issue before the S-cluster
// so softmax VALU hides both latencies. Defer-max (THR=4, exp2 domain) skips
// the alpha-rescale pass when the running max is stable.
__global__ __launch_bounds__(256) void attn_mfma(
    const _Float16* __restrict__ Qb, const _Float16* __restrict__ Kb,
    const _Float16* __restrict__ Vb, _Float16* __restrict__ Opart,
    float* __restrict__ Mv, float* __restrict__ Lv, _Float16* __restrict__ O)
{
    const int bh = blockIdx.y;
    const int wid = blockIdx.x;
    const int qblk = SEG_QBLK[wid];
    const int seg  = SEG_SEG[wid];
    const int q0 = qblk * 128;
    const int c0 = seg * 8;
    const int c1 = min(c0 + 8, 2 * qblk + 2);
    const bool solo = (c0 == 0) && (c1 == 2 * qblk + 2);
    const int tid = threadIdx.x;
    const int wave = tid >> 6, lane = tid & 63;
    const int m16 = lane & 15, quad = lane >> 4;
    const int sw = m16 & 7;

    __shared__ _Float16 Ps[8192];        // per-wave P scratch, 4 KB each
    _Float16* Pw = Ps + wave * 2048;

    const int qmin = q0 + wave * 32;
    const int qmax = qmin + 31;
    const int c1w = min(c1, (qmax >> 6) + 1);   // per-wave causal cutoff
    // (every chunk in [c0, c1w) has k0 <= qmin: k0 % 64 == 0, qmin % 32 == 0,
    //  and k0 <= qmax forces k0 <= qmin -> every row has >= 1 live key)

    // ---- Q fragments: direct from fragment-ordered blob ----
    const _Float16* gQ = Qb + ((size_t)bh * 16 + qblk) * 8192 + wave * 2048 + lane * 8;
    half8 qf[2][2];
#pragma unroll
    for (int mt = 0; mt < 2; mt++)
#pragma unroll
        for (int dh = 0; dh < 2; dh++)
            qf[mt][dh] = *(const half8*)&gQ[(mt * 2 + dh) * 512];

    // P LDS pointers (bank-swizzled by sw)
    _Float16* pwp[2][4];
    const _Float16* pfp[2][2];
#pragma unroll
    for (int mt = 0; mt < 2; mt++) {
#pragma unroll
        for (int kt = 0; kt < 4; kt++) {
            int kb = kt * 2 + (quad >> 1);
            pwp[mt][kt] = &Pw[(mt * 16 + m16) * 64 + ((kb ^ sw) << 3) + ((quad & 1) << 2)];
        }
#pragma unroll
        for (int kh = 0; kh < 2; kh++)
            pfp[mt][kh] = &Pw[(mt * 16 + m16) * 64 + (((kh * 4 + quad) ^ sw) << 3)];
    }

    float m_i[2] = {-INFINITY, -INFINITY}, l_i[2] = {0.f, 0.f};
    floatx4 acco[2][4];
    const floatx4 zf = {0.f, 0.f, 0.f, 0.f};
#pragma unroll
    for (int mt = 0; mt < 2; mt++)
#pragma unroll
        for (int dt = 0; dt < 4; dt++) acco[mt][dt] = zf;

    const _Float16* gK = Kb + ((size_t)bh * 32 + c0) * 4096 + lane * 8;
    const _Float16* gV = Vb + ((size_t)bh * 32 + c0) * 4096 + lane * 8;

    // preload K fragments for first chunk
    half8 kf[4][2];
#pragma unroll
    for (int kt = 0; kt < 4; kt++)
#pragma unroll
        for (int dh = 0; dh < 2; dh++)
            kf[kt][dh] = *(const half8*)&gK[(kt * 2 + dh) * 512];
    gK += 4096;

    for (int c = c0; c < c1w; c++) {
        const int k0 = c * 64;

        // V fragments for this chunk (latency hidden under S-cluster + softmax)
        half8 vf[4][2];
#pragma unroll
        for (int dt = 0; dt < 4; dt++)
#pragma unroll
            for (int kh = 0; kh < 2; kh++)
                vf[dt][kh] = *(const half8*)&gV[(dt * 2 + kh) * 512];
        gV += 4096;

        // ---- S^T = K.Q^T : 16 MFMAs ----
        floatx4 sf[2][4];
        __builtin_amdgcn_s_setprio(1);
#pragma unroll
        for (int kt = 0; kt < 4; kt++)
#pragma unroll
            for (int mt = 0; mt < 2; mt++)
                sf[mt][kt] = MFMA_F16(kf[kt][1], qf[mt][1],
                               MFMA_F16(kf[kt][0], qf[mt][0], zf));
        __builtin_amdgcn_s_setprio(0);

        // prefetch next K chunk (kf regs dead after the S-cluster)
        if (c + 1 < c1w) {
#pragma unroll
            for (int kt = 0; kt < 4; kt++)
#pragma unroll
                for (int dh = 0; dh < 2; dh++)
                    kf[kt][dh] = *(const half8*)&gK[(kt * 2 + dh) * 512];
            gK += 4096;
        }

        const bool full = (k0 + 63 <= qmin);
#pragma unroll
        for (int mt = 0; mt < 2; mt++) {
            const int qg = qmin + mt * 16 + m16;
            float mx = -INFINITY;
#pragma unroll
            for (int kt = 0; kt < 4; kt++)
#pragma unroll
                for (int r = 0; r < 4; r++) {
                    float v = sf[mt][kt][r];
                    if (!full) {
                        int key = k0 + kt * 16 + quad * 4 + r;
                        v = (key <= qg) ? v : -INFINITY;
                    }
                    sf[mt][kt][r] = v;
                    mx = fmaxf(mx, v);
                }
            mx = fmaxf(mx, __shfl_xor(mx, 16));
            mx = fmaxf(mx, __shfl_xor(mx, 32));
            float mn = m_i[mt];
            if (!__all(mx <= mn + RESCALE_THR)) {   // defer-max: skip rescale
                mn = fmaxf(mn, mx);
                float alpha = EXP2F(m_i[mt] - mn);
                m_i[mt] = mn;
                l_i[mt] *= alpha;
#pragma unroll
                for (int dt = 0; dt < 4; dt++) acco[mt][dt] *= alpha;
            }
            float ls = 0.f;
#pragma unroll
            for (int kt = 0; kt < 4; kt++) {
                float e0 = EXP2F(sf[mt][kt][0] - mn);
                float e1 = EXP2F(sf[mt][kt][1] - mn);
                float e2 = EXP2F(sf[mt][kt][2] - mn);
                float e3 = EXP2F(sf[mt][kt][3] - mn);
                ls += (e0 + e1) + (e2 + e3);
                H4 u;
                u.h2[0] = __builtin_amdgcn_cvt_pkrtz(e0, e1);
                u.h2[1] = __builtin_amdgcn_cvt_pkrtz(e2, e3);
                *(half4*)pwp[mt][kt] = u.h4;
            }
            ls += __shfl_xor(ls, 16);
            ls += __shfl_xor(ls, 32);
            l_i[mt] += ls;
        }
        asm volatile("s_waitcnt lgkmcnt(0)" ::: "memory");

        // ---- O^T += V^T.P : 16 MFMAs ----
        half8 pf[2][2];
#pragma unroll
        for (int mt = 0; mt < 2; mt++)
#pragma unroll
            for (int kh = 0; kh < 2; kh++)
                pf[mt][kh] = *(const half8*)pfp[mt][kh];
        __builtin_amdgcn_s_setprio(1);
#pragma unroll
        for (int dt = 0; dt < 4; dt++)
#pragma unroll
            for (int mt = 0; mt < 2; mt++)
                acco[mt][dt] = MFMA_F16(vf[dt][1], pf[mt][1],
                                 MFMA_F16(vf[dt][0], pf[mt][0], acco[mt][dt]));
        __builtin_amdgcn_s_setprio(0);
    }

    if (solo) {
        // ---- single segment: normalize and write O fp16 [B,S,E] directly ----
        const int b = bh >> 4;
        const int h = bh & (H_DIM - 1);
#pragma unroll
        for (int mt = 0; mt < 2; mt++) {
            float inv = 1.f / l_i[mt];
            int q = qmin + mt * 16 + m16;
            _Float16* dst = O + (size_t)(b * S_DIM + q) * E_DIM + h * 64;
#pragma unroll
            for (int dt = 0; dt < 4; dt++) {
                H4 u;
                u.h2[0] = __builtin_amdgcn_cvt_pkrtz(acco[mt][dt][0] * inv, acco[mt][dt][1] * inv);
                u.h2[1] = __builtin_amdgcn_cvt_pkrtz(acco[mt][dt][2] * inv, acco[mt][dt][3] * inv);
                *(half4*)&dst[dt * 16 + quad * 4] = u.h4;
            }
        }
    } else {
        // ---- write unnormalized partial + (m,l) ----
        const size_t prow = ((size_t)bh * 40 + SEG_BASE[qblk] + seg) * 128;
#pragma unroll
        for (int mt = 0; mt < 2; mt++) {
            int lq = wave * 32 + mt * 16 + m16;
            if (quad == 0) {
                Mv[prow + lq] = m_i[mt];
                Lv[prow + lq] = l_i[mt];
            }
            _Float16* dst = Opart + (prow + lq) * 64;
#pragma unroll
            for (int dt = 0; dt < 4; dt++) {
                H4 u;
                u.h2[0] = __builtin_amdgcn_cvt_pkrtz(acco[mt][dt][0], acco[mt][dt][1]);
                u.h2[1] = __builtin_amdgcn_cvt_pkrtz(acco[mt][dt][2], acco[mt][dt][3]);
                *(half4*)&dst[dt * 16 + quad * 4] = u.h4;
            }
        }
    }
}

// ---------------- combine partials -> O fp16 [B,S,E] (qb >= 4 only) ----------------
__global__ __launch_bounds__(256) void attn_combine(
    const _Float16* __restrict__ Opart, const float* __restrict__ Mv,
    const float* __restrict__ Lv, _Float16* __restrict__ O)
{
    const int qb = blockIdx.x + 4, bh = blockIdx.y;
    const int nseg = (qb >> 2) + 1;
    const size_t pbase = ((size_t)bh * 40 + SEG_BASE[qb]) * 128;
    const int t = threadIdx.x;
    const int r = t >> 1, dh = (t & 1) * 32;

    float m_s[4], w[4];
    float M = -INFINITY;
    for (int s = 0; s < nseg; s++) {
        m_s[s] = Mv[pbase + s * 128 + r];
        M = fmaxf(M, m_s[s]);
    }
    float L = 0.f;
    for (int s = 0; s < nseg; s++) {
        w[s] = EXP2F(m_s[s] - M);
        L += Lv[pbase + s * 128 + r] * w[s];
    }
    const float invL = 1.f / L;

    const int b = bh >> 4, h = bh & (H_DIM - 1);
    const int q = qb * 128 + r;
    _Float16* dst = O + (size_t)(b * S_DIM + q) * E_DIM + h * 64 + dh;
#pragma unroll
    for (int d0 = 0; d0 < 32; d0 += 8) {
        float acc[8] = {0.f, 0.f, 0.f, 0.f, 0.f, 0.f, 0.f, 0.f};
        for (int s = 0; s < nseg; s++) {
            half8 v = *(const half8*)&Opart[(pbase + s * 128 + r) * 64 + dh + d0];
#pragma unroll
            for (int j = 0; j < 8; j++) acc[j] += w[s] * (float)v[j];
        }
        half8 o;
#pragma unroll
        for (int j = 0; j < 8; j++) o[j] = (_Float16)(acc[j] * invL);
        *(half8*)&dst[d0] = o;
    }
}

// ---------------- launch ----------------
extern "C" void kernel_launch(void* const* d_in, const int* in_sizes, int n_in,
                              void* d_out, int out_size, void* d_ws, size_t ws_size,
                              hipStream_t stream) {
    const float* x  = (const float*)d_in[0];
    const float* Wq = (const float*)d_in[1];
    const float* bq = (const float*)d_in[2];
    const float* Wk = (const float*)d_in[3];
    const float* bk = (const float*)d_in[4];
    const float* Wv = (const float*)d_in[5];
    const float* bv = (const float*)d_in[6];
    const float* Wo = (const float*)d_in[7];
    const float* bo = (const float*)d_in[8];

    const size_t SZ = (size_t)M_DIM * E_DIM;   // 8 Mi elements
    const size_t WZ = (size_t)E_DIM * E_DIM;
    _Float16* Xh = (_Float16*)d_ws;            // 16 MB (reused as Oh)
    _Float16* Tq = Xh + SZ;
    _Float16* Tk = Tq + WZ;
    _Float16* Tv = Tk + WZ;
    _Float16* To = Tv + WZ;
    _Float16* Qb = To + WZ;                    // fragment-ordered blobs, 16 MB each
    _Float16* Kb = Qb + SZ;
    _Float16* Vb = Kb + SZ;
    _Float16* Opart = Vb + SZ;                 // 2560 * 8192 fp16 = 41.9 MB
    float* Mv = (float*)(Opart + (size_t)2560 * 8192);   // 2560*128 fp32
    float* Lv = Mv + 2560 * 128;
    _Float16* Oh = Xh;                         // alias: x dead after qkv_mfma

    cvt_x<<<dim3(M_DIM * E_DIM / 2048), 256, 0, stream>>>(x, Xh);
    cvt_w<<<dim3(16, 16, 4), 256, 0, stream>>>(Wq, Wk, Wv, Wo, Tq, Tk, Tv, To);

    qkv_mfma<<<dim3(M_DIM / 128, E_DIM / 128, 3), 256, 0, stream>>>(
        Xh, Tq, bq, Tk, bk, Tv, bv, Qb, Kb, Vb);

    attn_mfma<<<dim3(40, B_DIM * H_DIM), 256, 0, stream>>>(
        Qb, Kb, Vb, Opart, Mv, Lv, Oh);

    attn_combine<<<dim3(12, B_DIM * H_DIM), 256, 0, stream>>>(Opart, Mv, Lv, Oh);

    out_mfma<<<dim3(M_DIM / 128, E_DIM / 128), 256, 0, stream>>>(
        Oh, To, bo, (float*)d_out);
}